// Round 13
// baseline (194.015 us; speedup 1.0000x reference)
//
#include <hip/hip_runtime.h>
#include <hip/hip_bf16.h>

// PriorScaleShift:
//   x:         (B=1024, S=512) int32 token ids in [0, 32000)
//   mask:      (B, S, 1) float32  (nonnegative)
//   log_scale: (1, 1, V=32000) float32
//   shift:     (1, 1, V) float32
//   out:       (B, 1, V) float32 = exp(log_scale)*presence + shift
// presence[b,v] = 1 iff exists s: x[b,s]==v and mask[b,s] > 0.
//
// Round 13: two stream-ordered kernels, no barriers anywhere.
//   kernel A (copy): out[b,:] = shift[:] via nontemporal 16B stores.
//     4096 blocks x 256 threads, quarter-row each — structurally identical
//     to the harness fill kernel that sustains 6.5 TB/s on this machine.
//     shift reads are L2-hot (128 KB). No barrier, no divergence, no LDS.
//   kernel B (fixup): one (row,s) pair per thread; if mask>0:
//     out[row,v] = expf(ls[v]) + sh[v]. ~512K scattered 4B stores (~5 us).
//     Stream order guarantees A's stores precede B's.
//   Duplicate (row,v) fixups write identical values -> benign race.

#define PSS_VOCAB 32000
#define PSS_SEQ   512
#define PSS_QF4   (PSS_VOCAB / 4 / 4)   // 2000 float4 per quarter-row

typedef float v4f __attribute__((ext_vector_type(4)));

__global__ __launch_bounds__(256)
void pss_copy_kernel(const float* __restrict__ shift,
                     float* __restrict__ out) {
    const int bid = blockIdx.x;
    const int row = bid >> 2;
    const int q   = bid & 3;
    const int t   = threadIdx.x;

    const v4f* s4 = (const v4f*)(shift + q * (PSS_VOCAB / 4));
    v4f*       o4 = (v4f*)(out + (size_t)row * PSS_VOCAB + q * (PSS_VOCAB / 4));

    #pragma unroll 4
    for (int i = t; i < PSS_QF4; i += 256)
        __builtin_nontemporal_store(s4[i], &o4[i]);
}

__global__ __launch_bounds__(256)
void PriorScaleShift_47467978556092_kernel(const int* __restrict__ x,
                                           const float* __restrict__ mask,
                                           const float* __restrict__ log_scale,
                                           const float* __restrict__ shift,
                                           float* __restrict__ out) {
    const int idx = blockIdx.x * 256 + threadIdx.x;   // (row, s) flat
    const int row = idx >> 9;                          // / PSS_SEQ
    const int v   = x[idx];
    const float m = mask[idx];
    if (m > 0.0f)
        out[(size_t)row * PSS_VOCAB + v] = expf(log_scale[v]) + shift[v];
}

extern "C" void kernel_launch(void* const* d_in, const int* in_sizes, int n_in,
                              void* d_out, int out_size, void* d_ws, size_t ws_size,
                              hipStream_t stream) {
    const int*   x         = (const int*)d_in[0];
    const float* mask      = (const float*)d_in[1];
    const float* log_scale = (const float*)d_in[2];
    const float* shift     = (const float*)d_in[3];
    float* out = (float*)d_out;

    const int batch = in_sizes[0] / PSS_SEQ;   // 1024

    pss_copy_kernel<<<batch * 4, 256, 0, stream>>>(shift, out);

    PriorScaleShift_47467978556092_kernel<<<(batch * PSS_SEQ) / 256, 256, 0, stream>>>(
        x, mask, log_scale, shift, out);
}